// Round 7
// baseline (2391.770 us; speedup 1.0000x reference)
//
#include <hip/hip_runtime.h>
#include <math.h>

#define CC 32
typedef _Float16 f16;

static inline int cdiv(long long a, int b) { return (int)((a + b - 1) / b); }

union U8 { int4 i; f16 v[8]; };

// unpack 8 interleaved f16 (c*2+hd layout) -> two float4 (head0, head1)
__device__ inline void unpack8(int4 raw, float4& a0, float4& a1) {
  U8 u;
  u.i = raw;
  a0 = make_float4((float)u.v[0], (float)u.v[2], (float)u.v[4], (float)u.v[6]);
  a1 = make_float4((float)u.v[1], (float)u.v[3], (float)u.v[5], (float)u.v[7]);
}

// ---------- fp32 -> fp16 cast ----------
__global__ void k_cast(const float* __restrict__ x, f16* __restrict__ o, long long n) {
  long long i = (long long)blockIdx.x * blockDim.x + threadIdx.x;
  if (i < n) o[i] = (f16)x[i];
}

// ---------- degree histogram ----------
__global__ void k_degcnt(const int* __restrict__ src, const int* __restrict__ dst,
                         float* __restrict__ deg, int* __restrict__ cnt, int E) {
  int i = blockIdx.x * blockDim.x + threadIdx.x;
  if (i < E) {
    atomicAdd(&deg[src[i]], 1.0f);
    atomicAdd(&cnt[dst[i]], 1);
  }
}

__global__ void k_dis(float* __restrict__ dis, int N) {
  int i = blockIdx.x * blockDim.x + threadIdx.x;
  if (i < N) {
    float d = dis[i];
    dis[i] = (d > 0.f) ? rsqrtf(fmaxf(d, 1.f)) : 0.f;
  }
}

// ---------- single-block exclusive scan ----------
__global__ void k_scan(const int* __restrict__ cnt, int* __restrict__ rowptr,
                       int* __restrict__ cur, int N) {
  const int T = 1024;
  __shared__ int ps[T];
  int t = threadIdx.x;
  int chunk = (N + T - 1) / T;
  int lo = t * chunk, hi = min(lo + chunk, N);
  int s = 0;
  for (int i = lo; i < hi; ++i) s += cnt[i];
  ps[t] = s;
  __syncthreads();
  for (int off = 1; off < T; off <<= 1) {
    int v = (t >= off) ? ps[t - off] : 0;
    __syncthreads();
    ps[t] += v;
    __syncthreads();
  }
  int run = (t == 0) ? 0 : ps[t - 1];
  for (int i = lo; i < hi; ++i) {
    rowptr[i] = run;
    cur[i] = run;
    run += cnt[i];
  }
  if (t == T - 1) rowptr[N] = run;
}

// ---------- CSR fill: col + wdis (=dis[src], f16) ----------
__global__ void k_fill(const int* __restrict__ src, const int* __restrict__ dst,
                       const float* __restrict__ dis, int* __restrict__ cur,
                       int* __restrict__ col, f16* __restrict__ wdis, int E) {
  int i = blockIdx.x * blockDim.x + threadIdx.x;
  if (i < E) {
    int s = src[i];
    int p = atomicAdd(&cur[dst[i]], 1);
    col[p] = s;
    wdis[p] = (f16)dis[s];
  }
}

// ---------- chebacc init: out = bias + patch @ W0 ----------
__global__ void k_init(const float* __restrict__ T, const float* __restrict__ W,
                       const float* __restrict__ bias, float* __restrict__ out, int N) {
  __shared__ float w[1024];
  for (int i = threadIdx.x; i < 1024; i += blockDim.x) w[i] = W[i];
  __syncthreads();
  int row = blockIdx.x * 8 + threadIdx.x / 32;
  int c = threadIdx.x & 31;
  if (row >= N) return;
  const float* tr = T + (long long)row * 32;
  float acc = bias[c];
#pragma unroll
  for (int cc = 0; cc < 32; ++cc) acc = fmaf(tr[cc], w[cc * 32 + c], acc);
  out[(long long)row * 32 + c] = acc;
}

// ---------- Cheb propagation: block owns 64 dst nodes, thread-per-edge gather,
// LDS accumulate (bank-padded), fused recurrence + GEMM epilogue ----------
__global__ void k_prop(const f16* __restrict__ xh, const float* __restrict__ prev,
                       const int* __restrict__ rowptr, const int* __restrict__ col,
                       const f16* __restrict__ wdis, const float* __restrict__ dis,
                       const float* __restrict__ W, float* __restrict__ out,
                       f16* __restrict__ outh, float* __restrict__ chebacc,
                       float scale, float prevscale, int N) {
  const int NB = 64;
  __shared__ float accs[NB * 33];
  __shared__ float w0[1024];
  __shared__ int rp[NB + 1];
  int tid = threadIdx.x;
  int n0 = blockIdx.x * NB;
  for (int i = tid; i < 1024; i += 256) w0[i] = W[i];
  for (int i = tid; i < NB * 33; i += 256) accs[i] = 0.f;
  for (int i = tid; i <= NB; i += 256) rp[i] = rowptr[min(n0 + i, N)];
  __syncthreads();
  int eLo = rp[0], eHi = rp[NB];
  for (int j = eLo + tid; j < eHi; j += 256) {
    int s = col[j];
    float wd = (float)wdis[j];
    const int4* p4 = (const int4*)(xh + (long long)s * 32);
    U8 a, b, c2, d;
    a.i = p4[0]; b.i = p4[1]; c2.i = p4[2]; d.i = p4[3];
    // binary search local dst: rp[dl] <= j < rp[dl+1]
    int blo = 0, bhi = NB;
    while (bhi - blo > 1) {
      int md = (blo + bhi) >> 1;
      if (j >= rp[md]) blo = md; else bhi = md;
    }
    float* arow = &accs[blo * 33];
#pragma unroll
    for (int k = 0; k < 8; ++k) atomicAdd(&arow[k], wd * (float)a.v[k]);
#pragma unroll
    for (int k = 0; k < 8; ++k) atomicAdd(&arow[8 + k], wd * (float)b.v[k]);
#pragma unroll
    for (int k = 0; k < 8; ++k) atomicAdd(&arow[16 + k], wd * (float)c2.v[k]);
#pragma unroll
    for (int k = 0; k < 8; ++k) atomicAdd(&arow[24 + k], wd * (float)d.v[k]);
  }
  __syncthreads();
  int c = tid & 31, g8 = tid >> 5;
  // pass 1: recurrence, write Tx (each (nl,c) owned by one thread)
#pragma unroll
  for (int rep = 0; rep < 8; ++rep) {
    int nl = rep * 8 + g8;
    int gg = n0 + nl;
    if (gg < N) {
      float t = -dis[gg] * scale * accs[nl * 33 + c];
      if (prev) t = fmaf(prevscale, prev[(long long)gg * 32 + c], t);
      accs[nl * 33 + c] = t;
      if (out) out[(long long)gg * 32 + c] = t;
      if (outh) outh[(long long)gg * 32 + c] = (f16)t;
    }
  }
  __syncthreads();
  // pass 2: chebacc += Tx @ W (LDS broadcast reads)
#pragma unroll
  for (int rep = 0; rep < 8; ++rep) {
    int nl = rep * 8 + g8;
    int gg = n0 + nl;
    if (gg < N) {
      float o = chebacc[(long long)gg * 32 + c];
#pragma unroll
      for (int cc = 0; cc < 32; ++cc) o = fmaf(accs[nl * 33 + cc], w0[cc * 32 + c], o);
      chebacc[(long long)gg * 32 + c] = o;
    }
  }
}

// ---------- h = x @ lin_w, fp16 head-interleaved: hh[row][c*2+hd] ----------
__global__ void k_gemm64(const float* __restrict__ T, const float* __restrict__ W,
                         f16* __restrict__ hh, int N) {
  __shared__ float w[2048];
  for (int i = threadIdx.x; i < 2048; i += blockDim.x) w[i] = W[i];
  __syncthreads();
  int row = blockIdx.x * 4 + threadIdx.x / 64;
  int colx = threadIdx.x % 64;  // hd*32+c
  if (row >= N) return;
  const float* tr = T + (long long)row * 32;
  float acc = 0.f;
#pragma unroll
  for (int c = 0; c < 32; ++c) acc += tr[c] * w[c * 64 + colx];
  int c = colx & 31, hd = colx >> 5;
  hh[(long long)row * 64 + c * 2 + hd] = (f16)acc;
}

// ---------- proj vectors ----------
__global__ void k_proj(const float* __restrict__ lin_w, const float* __restrict__ attl,
                       const float* __restrict__ attr, float* __restrict__ proj) {
  int t = threadIdx.x;
  if (t < 128) {
    int v = t >> 5, c = t & 31;
    int hd = v & 1;
    const float* att = (v < 2) ? attl : attr;
    float s = 0.f;
    for (int j = 0; j < 32; ++j) s += lin_w[c * 64 + hd * 32 + j] * att[hd * 32 + j];
    proj[v * 32 + c] = s;
  }
}

// ---------- per-node attention terms ----------
__global__ void k_nodeatt(const float* __restrict__ x, const float* __restrict__ proj,
                          float* __restrict__ natt, int N) {
  __shared__ float pj[128];
  if (threadIdx.x < 128) pj[threadIdx.x] = proj[threadIdx.x];
  __syncthreads();
  int g = (blockIdx.x * blockDim.x + threadIdx.x) >> 5;
  int c = threadIdx.x & 31;
  if (g >= N) return;
  float xv = x[(long long)g * 32 + c];
  float d0 = xv * pj[c], d1 = xv * pj[32 + c], d2 = xv * pj[64 + c], d3 = xv * pj[96 + c];
#pragma unroll
  for (int m = 16; m; m >>= 1) {
    d0 += __shfl_xor(d0, m, 32);
    d1 += __shfl_xor(d1, m, 32);
    d2 += __shfl_xor(d2, m, 32);
    d3 += __shfl_xor(d3, m, 32);
  }
  if (c == 0) *(float4*)(natt + (long long)g * 4) = make_float4(d0, d1, d2, d3);
}

// ---------- SuperGAT: wave/node, 8 edge slots x 8 lanes, 4-batch register prefetch ----------
__global__ void k_gat(const f16* __restrict__ h, const int* __restrict__ rowptr,
                      const int* __restrict__ col, const float* __restrict__ natt,
                      const float* __restrict__ gb, float* __restrict__ y, int N) {
  int wv = (blockIdx.x * blockDim.x + threadIdx.x) >> 6;
  int lane = threadIdx.x & 63;
  int e = lane >> 3, q = lane & 7;
  if (wv >= N) return;
  float4 own0, own1;
  unpack8(*(const int4*)(h + (long long)wv * 64 + q * 8), own0, own1);
  const float4 na = *(const float4*)(natt + (long long)wv * 4);  // {al0,al1,ar0,ar1}
  // self-loop alpha
  float d0 = own0.x * own0.x + own0.y * own0.y + own0.z * own0.z + own0.w * own0.w;
  float d1 = own1.x * own1.x + own1.y * own1.y + own1.z * own1.z + own1.w * own1.w;
#pragma unroll
  for (int m = 1; m <= 4; m <<= 1) { d0 += __shfl_xor(d0, m); d1 += __shfl_xor(d1, m); }
  float a0 = (na.x + na.z) / (1.f + __expf(-d0));
  float a1 = (na.y + na.w) / (1.f + __expf(-d1));
  a0 = (a0 > 0.f) ? a0 : 0.2f * a0;
  a1 = (a1 > 0.f) ? a1 : 0.2f * a1;
  // per-slot state (slot 0 seeds the self-loop)
  float m0, m1, l0, l1;
  float4 acc0, acc1;
  if (e == 0) {
    m0 = a0; m1 = a1; l0 = 1.f; l1 = 1.f;
    acc0 = own0; acc1 = own1;
  } else {
    m0 = -1e30f; m1 = -1e30f; l0 = 0.f; l1 = 0.f;
    acc0 = make_float4(0, 0, 0, 0); acc1 = make_float4(0, 0, 0, 0);
  }
  int lo = rowptr[wv], hi = rowptr[wv + 1];
  int deg = hi - lo;
  int nb = (deg + 7) >> 3;
  // prefetch up to 4 batches of rows + natt into registers (independent loads)
  int4 rv[4]; float2 av[4]; bool vv[4];
#pragma unroll
  for (int b = 0; b < 4; ++b) {
    if (b < nb) {
      int off = b * 8 + e;
      bool valid = off < deg;
      int s = col[valid ? (lo + off) : (hi - 1)];
      rv[b] = *(const int4*)(h + (long long)s * 64 + q * 8);
      av[b] = *(const float2*)(natt + (long long)s * 4);
      vv[b] = valid;
    }
  }
#pragma unroll
  for (int b = 0; b < 4; ++b) {
    if (b < nb) {
      float4 h0, h1;
      unpack8(rv[b], h0, h1);
      float t0 = h0.x * own0.x + h0.y * own0.y + h0.z * own0.z + h0.w * own0.w;
      float t1 = h1.x * own1.x + h1.y * own1.y + h1.z * own1.z + h1.w * own1.w;
#pragma unroll
      for (int m = 1; m <= 4; m <<= 1) { t0 += __shfl_xor(t0, m); t1 += __shfl_xor(t1, m); }
      float ae0 = (av[b].x + na.z) / (1.f + __expf(-t0));
      float ae1 = (av[b].y + na.w) / (1.f + __expf(-t1));
      ae0 = (ae0 > 0.f) ? ae0 : 0.2f * ae0;
      ae1 = (ae1 > 0.f) ? ae1 : 0.2f * ae1;
      if (vv[b]) {
        float mn0 = fmaxf(m0, ae0), mn1 = fmaxf(m1, ae1);
        float sc0 = __expf(m0 - mn0), sc1 = __expf(m1 - mn1);
        float f0 = __expf(ae0 - mn0), f1 = __expf(ae1 - mn1);
        l0 = l0 * sc0 + f0;
        l1 = l1 * sc1 + f1;
        acc0.x = acc0.x * sc0 + f0 * h0.x; acc0.y = acc0.y * sc0 + f0 * h0.y;
        acc0.z = acc0.z * sc0 + f0 * h0.z; acc0.w = acc0.w * sc0 + f0 * h0.w;
        acc1.x = acc1.x * sc1 + f1 * h1.x; acc1.y = acc1.y * sc1 + f1 * h1.y;
        acc1.z = acc1.z * sc1 + f1 * h1.z; acc1.w = acc1.w * sc1 + f1 * h1.w;
        m0 = mn0; m1 = mn1;
      }
    }
  }
  // rare tail (deg > 32)
  for (int j = lo + 32; j < hi; j += 8) {
    int jj = j + e;
    bool valid = jj < hi;
    int s = col[valid ? jj : (hi - 1)];
    float4 h0, h1;
    unpack8(*(const int4*)(h + (long long)s * 64 + q * 8), h0, h1);
    float2 al = *(const float2*)(natt + (long long)s * 4);
    float t0 = h0.x * own0.x + h0.y * own0.y + h0.z * own0.z + h0.w * own0.w;
    float t1 = h1.x * own1.x + h1.y * own1.y + h1.z * own1.z + h1.w * own1.w;
#pragma unroll
    for (int m = 1; m <= 4; m <<= 1) { t0 += __shfl_xor(t0, m); t1 += __shfl_xor(t1, m); }
    float ae0 = (al.x + na.z) / (1.f + __expf(-t0));
    float ae1 = (al.y + na.w) / (1.f + __expf(-t1));
    ae0 = (ae0 > 0.f) ? ae0 : 0.2f * ae0;
    ae1 = (ae1 > 0.f) ? ae1 : 0.2f * ae1;
    if (valid) {
      float mn0 = fmaxf(m0, ae0), mn1 = fmaxf(m1, ae1);
      float sc0 = __expf(m0 - mn0), sc1 = __expf(m1 - mn1);
      float f0 = __expf(ae0 - mn0), f1 = __expf(ae1 - mn1);
      l0 = l0 * sc0 + f0;
      l1 = l1 * sc1 + f1;
      acc0.x = acc0.x * sc0 + f0 * h0.x; acc0.y = acc0.y * sc0 + f0 * h0.y;
      acc0.z = acc0.z * sc0 + f0 * h0.z; acc0.w = acc0.w * sc0 + f0 * h0.w;
      acc1.x = acc1.x * sc1 + f1 * h1.x; acc1.y = acc1.y * sc1 + f1 * h1.y;
      acc1.z = acc1.z * sc1 + f1 * h1.z; acc1.w = acc1.w * sc1 + f1 * h1.w;
      m0 = mn0; m1 = mn1;
    }
  }
  // merge the 8 slot states (flash-attention merge across lanes 8,16,32)
#pragma unroll
  for (int m = 8; m <= 32; m <<= 1) {
    float om0 = __shfl_xor(m0, m), om1 = __shfl_xor(m1, m);
    float ol0 = __shfl_xor(l0, m), ol1 = __shfl_xor(l1, m);
    float4 oa0 = make_float4(__shfl_xor(acc0.x, m), __shfl_xor(acc0.y, m),
                             __shfl_xor(acc0.z, m), __shfl_xor(acc0.w, m));
    float4 oa1 = make_float4(__shfl_xor(acc1.x, m), __shfl_xor(acc1.y, m),
                             __shfl_xor(acc1.z, m), __shfl_xor(acc1.w, m));
    float mn0 = fmaxf(m0, om0), mn1 = fmaxf(m1, om1);
    float fa0 = __expf(m0 - mn0), fb0 = __expf(om0 - mn0);
    float fa1 = __expf(m1 - mn1), fb1 = __expf(om1 - mn1);
    l0 = l0 * fa0 + ol0 * fb0;
    l1 = l1 * fa1 + ol1 * fb1;
    acc0.x = acc0.x * fa0 + oa0.x * fb0; acc0.y = acc0.y * fa0 + oa0.y * fb0;
    acc0.z = acc0.z * fa0 + oa0.z * fb0; acc0.w = acc0.w * fa0 + oa0.w * fb0;
    acc1.x = acc1.x * fa1 + oa1.x * fb1; acc1.y = acc1.y * fa1 + oa1.y * fb1;
    acc1.z = acc1.z * fa1 + oa1.z * fb1; acc1.w = acc1.w * fa1 + oa1.w * fb1;
    m0 = mn0; m1 = mn1;
  }
  if (e == 0) {
    float r0 = 1.f / l0, r1 = 1.f / l1;
    const float4 gb4 = *(const float4*)(gb + q * 4);
    float4 yv;
    float v;
    v = 0.5f * (acc0.x * r0 + acc1.x * r1) + gb4.x; yv.x = ((v > 0.f) ? v : 0.01f * v) + v;
    v = 0.5f * (acc0.y * r0 + acc1.y * r1) + gb4.y; yv.y = ((v > 0.f) ? v : 0.01f * v) + v;
    v = 0.5f * (acc0.z * r0 + acc1.z * r1) + gb4.z; yv.z = ((v > 0.f) ? v : 0.01f * v) + v;
    v = 0.5f * (acc0.w * r0 + acc1.w * r1) + gb4.w; yv.w = ((v > 0.f) ? v : 0.01f * v) + v;
    *(float4*)(y + (long long)wv * 32 + q * 4) = yv;
  }
}

// ---------- BN stats: 256-block grid-stride reduce of y ----------
__global__ void k_bnstats(const float* __restrict__ y, float* __restrict__ bns,
                          long long n4) {
  __shared__ float ls[64];
  int tid = threadIdx.x;
  if (tid < 64) ls[tid] = 0.f;
  __syncthreads();
  float s[4] = {0, 0, 0, 0}, sq[4] = {0, 0, 0, 0};
  for (long long idx = blockIdx.x * 256 + tid; idx < n4; idx += (long long)gridDim.x * 256) {
    float4 v = ((const float4*)y)[idx];
    s[0] += v.x; sq[0] += v.x * v.x;
    s[1] += v.y; sq[1] += v.y * v.y;
    s[2] += v.z; sq[2] += v.z * v.z;
    s[3] += v.w; sq[3] += v.w * v.w;
  }
  int c0 = (tid * 4) & 31;
#pragma unroll
  for (int k = 0; k < 4; ++k) {
    atomicAdd(&ls[c0 + k], s[k]);
    atomicAdd(&ls[32 + c0 + k], sq[k]);
  }
  __syncthreads();
  if (tid < 64) atomicAdd(&bns[tid], ls[tid]);
}

__global__ void k_bnfinal(const float* __restrict__ y, const float* __restrict__ bns,
                          const float* __restrict__ g, const float* __restrict__ b,
                          float* __restrict__ out, int N) {
  int i = blockIdx.x * blockDim.x + threadIdx.x;
  if (i >= N * CC) return;
  int c = i & 31;
  float inv_n = 1.f / (float)N;
  float mu = bns[c] * inv_n;
  float var = bns[32 + c] * inv_n - mu * mu;
  out[i] = (y[i] - mu) * rsqrtf(var + 1e-5f) * g[c] + b[c];
}

extern "C" void kernel_launch(void* const* d_in, const int* in_sizes, int n_in,
                              void* d_out, int out_size, void* d_ws, size_t ws_size,
                              hipStream_t stream) {
  const float* patch = (const float*)d_in[0];
  const int* eidx = (const int*)d_in[1];
  const float* cheb_w = (const float*)d_in[3];
  const float* cheb_b = (const float*)d_in[4];
  const float* lin_w = (const float*)d_in[5];
  const float* att_l = (const float*)d_in[6];
  const float* att_r = (const float*)d_in[7];
  const float* gat_b = (const float*)d_in[8];
  const float* bn_g = (const float*)d_in[9];
  const float* bn_b = (const float*)d_in[10];
  float* out = (float*)d_out;

  const int N = in_sizes[0] / CC;  // 100000
  const int E = in_sizes[1] / 2;   // 1600000
  const int* src = eidx;
  const int* dst = eidx + E;

  // workspace (~50 MB)
  float* TxA = (float*)d_ws;                  // N*32 f (hh overlays later)
  float* TxB = TxA + (size_t)N * 32;          // N*32 f
  f16* xhA = (f16*)(TxB + (size_t)N * 32);    // N*32 f16
  f16* xhB = xhA + (size_t)N * 32;            // N*32 f16
  int* col = (int*)(xhB + (size_t)N * 32);    // E
  f16* wdis = (f16*)(col + E);                // E f16 (natt overlays after props)
  float* natt = (float*)wdis;                 // N*4 (16B aligned)
  int* rowptr = (int*)(wdis + E);             // N+4
  int* cur = rowptr + N + 4;                  // N
  int* cnt = cur + N;                         // N
  float* deg = (float*)(cnt + N);             // N (dis in place)
  float* proj = deg + N;                      // 128
  float* bns = proj + 128;                    // 64
  f16* hh = (f16*)TxA;                        // N*64 f16 == N*32 f

  const int B = 256;
  const long long NC = (long long)N * 32;

  hipMemsetAsync(cnt, 0, sizeof(int) * (size_t)N * 2, stream);  // cnt + deg
  hipMemsetAsync(bns, 0, sizeof(float) * 64, stream);

  // CSR + norm + fp16 patch
  k_cast<<<cdiv(NC, B), B, 0, stream>>>(patch, xhA, NC);
  k_degcnt<<<cdiv(E, B), B, 0, stream>>>(src, dst, deg, cnt, E);
  k_dis<<<cdiv(N, B), B, 0, stream>>>(deg, N);
  k_scan<<<1, 1024, 0, stream>>>(cnt, rowptr, cur, N);
  k_fill<<<cdiv(E, B), B, 0, stream>>>(src, dst, deg, cur, col, wdis, E);

  // chebacc = bias + patch @ W0
  k_init<<<cdiv(N, 8), B, 0, stream>>>(patch, cheb_w, cheb_b, out, N);
  // Tx1 = prop(patch): gather xhA -> TxA f32 + xhB f16; chebacc += Tx1@W1
  k_prop<<<cdiv(N, 64), B, 0, stream>>>(xhA, nullptr, rowptr, col, wdis, deg,
                                        cheb_w + 1 * 1024, TxA, xhB, out, 1.f, 0.f, N);
  // Tx2 = 2*prop(Tx1) - patch: gather xhB -> TxB + xhA; += Tx2@W2
  k_prop<<<cdiv(N, 64), B, 0, stream>>>(xhB, patch, rowptr, col, wdis, deg,
                                        cheb_w + 2 * 1024, TxB, xhA, out, 2.f, -1.f, N);
  // Tx3 = 2*prop(Tx2) - Tx1: gather xhA, prev=TxA -> xhB only; += Tx3@W3
  k_prop<<<cdiv(N, 64), B, 0, stream>>>(xhA, TxA, rowptr, col, wdis, deg,
                                        cheb_w + 3 * 1024, nullptr, xhB, out, 2.f, -1.f, N);
  // Tx4 = 2*prop(Tx3) - Tx2: gather xhB, prev=TxB -> nothing; += Tx4@W4
  k_prop<<<cdiv(N, 64), B, 0, stream>>>(xhB, TxB, rowptr, col, wdis, deg,
                                        cheb_w + 4 * 1024, nullptr, nullptr, out, 2.f, -1.f, N);

  // SuperGAT (natt overlays wdis: wdis dead after props)
  k_proj<<<1, 128, 0, stream>>>(lin_w, att_l, att_r, proj);
  k_nodeatt<<<cdiv(NC, B), B, 0, stream>>>(out, proj, natt, N);
  k_gemm64<<<cdiv(N, 4), B, 0, stream>>>(out, lin_w, hh, N);  // hh overlays TxA (dead)
  k_gat<<<cdiv(N, 4), B, 0, stream>>>(hh, rowptr, col, natt, gat_b, out, N);

  // BatchNorm stats + finalize (in place on d_out)
  k_bnstats<<<256, B, 0, stream>>>(out, bns, NC / 4);
  k_bnfinal<<<cdiv(NC, B), B, 0, stream>>>(out, bns, bn_g, bn_b, out, N);
}